// Round 3
// baseline (2917.572 us; speedup 1.0000x reference)
//
#include <hip/hip_runtime.h>
#include <math.h>

#define NU      256
#define NLAYERS 6
#define NBATCH  32768
#define NDIN    784
#define NDOUT   10

#define BM 128
#define BN 128
#define BK 16

// 16-way static-index dispatch over a wave-uniform row index. Keeps a[16][4]
// in VGPRs (dynamic indices -> scratch spill).
#define ROW_CASES(BODY) \
    case 0:  BODY(0);  break; case 1:  BODY(1);  break; \
    case 2:  BODY(2);  break; case 3:  BODY(3);  break; \
    case 4:  BODY(4);  break; case 5:  BODY(5);  break; \
    case 6:  BODY(6);  break; case 7:  BODY(7);  break; \
    case 8:  BODY(8);  break; case 9:  BODY(9);  break; \
    case 10: BODY(10); break; case 11: BODY(11); break; \
    case 12: BODY(12); break; case 13: BODY(13); break; \
    case 14: BODY(14); break; case 15: BODY(15); break;

// ---------------------------------------------------------------------------
// In-place Gauss-Jordan inversion with partial (row) pivoting. One block of
// 1024 threads per layer. Thread (ct, rt): ct = tid&63 owns cols ct*4..ct*4+3;
// rt = tid>>6 (== wave id) owns rows rt*16..rt*16+15, register-resident.
// 3 barriers/iteration:
//   P0 (pre-bar): lane ctk of each wave scans its own 16 column-k register
//       values -> one (absval, signedval, row) candidate per wave to LDS.
//   P1: all waves redundantly shuffle-reduce the 16 candidates -> pivot row p;
//       waves rtk/rtp stage rows k/p to LDS for the physical swap.
//   P2: wave rtk scales old-row-p by pivinv, installs at slot ik, publishes to
//       double-buffered prow; wave rtp installs old-row-k at slot ip.
//   P3: elimination. Column-k values come from __shfl(a[i][jk], ctk) (uniform
//       source lane -> v_readlane, no LDS, no extra barrier).
// Final column unscramble (NR: reverse swaps) applied as a permutation at the
// global write. __launch_bounds__(1024,4): VGPR cap 128 so a[16][4] fits
// (round-2's default targeted 64 VGPR -> scratch spill -> 800us).
// ---------------------------------------------------------------------------
__global__ __launch_bounds__(1024, 4) void invert_kernel(
    const float* __restrict__ B0, float* __restrict__ Minv)
{
    const int layer = blockIdx.x;
    const int tid = threadIdx.x;
    const int ct = tid & 63;
    const int rt = tid >> 6;

    __shared__ __align__(16) float4 prow[2][64];
    __shared__ __align__(16) float  rowK[256];
    __shared__ __align__(16) float  rowP[256];
    __shared__ float pv_a[16];
    __shared__ float pv_s[16];
    __shared__ int   pv_r[16];
    __shared__ int   indxr[256];
    __shared__ int   srccol[256];
    __shared__ int   invsrc[256];

    float a[16][4];
    const float* Ablk = B0 + (size_t)layer * NU * NU;
#pragma unroll
    for (int i = 0; i < 16; ++i) {
        const float4 v = *(const float4*)(Ablk + (size_t)(rt*16 + i)*NU + ct*4);
        a[i][0] = v.x; a[i][1] = v.y; a[i][2] = v.z; a[i][3] = v.w;
    }

    for (int k = 0; k < 256; ++k) {
        const int ctk = k >> 2, jk = k & 3;
        const int rtk = k >> 4, ik = k & 15;

        // ---- P0: per-wave pivot candidate from registers (lane ctk) ----
        if (ct == ctk) {
            float ba = -1.0f, bv = 1.0f; int br = k;
#define CAND(J) { _Pragma("unroll") for (int i = 0; i < 16; ++i) { \
                const int row = rt*16 + i; \
                const float sv = a[i][J]; \
                const float av = (row >= k) ? fabsf(sv) : -1.0f; \
                if (av > ba) { ba = av; bv = sv; br = row; } } }
            if      (jk == 0) CAND(0)
            else if (jk == 1) CAND(1)
            else if (jk == 2) CAND(2)
            else              CAND(3)
#undef CAND
            pv_a[rt] = ba; pv_s[rt] = bv; pv_r[rt] = br;
        }
        __syncthreads();                                   // bar1

        // ---- P1: all waves redundantly reduce the 16 candidates ----
        float ca, cv; int cr;
        if (ct < 16) { ca = pv_a[ct]; cv = pv_s[ct]; cr = pv_r[ct]; }
        else         { ca = -2.0f;    cv = 1.0f;     cr = k; }
#pragma unroll
        for (int off = 8; off > 0; off >>= 1) {
            const float oa = __shfl_down(ca, off);
            const float ov = __shfl_down(cv, off);
            const int   orr = __shfl_down(cr, off);
            if (oa > ca) { ca = oa; cv = ov; cr = orr; }
        }
        const int   p      = __shfl(cr, 0);
        const float pivinv = 1.0f / __shfl(cv, 0);
        if (tid == 0) indxr[k] = p;
        const int rtp = p >> 4, ip = p & 15;

        // stage rows k and p for the physical swap (static register reads)
        if (rt == rtk) {
            float r0, r1, r2, r3;
#define RD(I) { r0 = a[I][0]; r1 = a[I][1]; r2 = a[I][2]; r3 = a[I][3]; }
            switch (ik) { ROW_CASES(RD) }
#undef RD
            float4 v; v.x = r0; v.y = r1; v.z = r2; v.w = r3;
            *(float4*)(rowK + ct*4) = v;
        }
        if (rt == rtp) {
            float r0, r1, r2, r3;
#define RD(I) { r0 = a[I][0]; r1 = a[I][1]; r2 = a[I][2]; r3 = a[I][3]; }
            switch (ip) { ROW_CASES(RD) }
#undef RD
            float4 v; v.x = r0; v.y = r1; v.z = r2; v.w = r3;
            *(float4*)(rowP + ct*4) = v;
        }
        __syncthreads();                                   // bar2

        // ---- P2: install swap; scale new pivot row; publish scaled row ----
        if (rt == rtk) {
            const float4 v = *(const float4*)(rowP + ct*4);
            float w0 = v.x*pivinv, w1 = v.y*pivinv, w2 = v.z*pivinv, w3 = v.w*pivinv;
            if (ct == ctk) {                   // diagonal slot gets pivinv
                if      (jk == 0) w0 = pivinv;
                else if (jk == 1) w1 = pivinv;
                else if (jk == 2) w2 = pivinv;
                else              w3 = pivinv;
            }
#define WR(I) { a[I][0] = w0; a[I][1] = w1; a[I][2] = w2; a[I][3] = w3; }
            switch (ik) { ROW_CASES(WR) }
#undef WR
            float4 w; w.x = w0; w.y = w1; w.z = w2; w.w = w3;
            prow[k & 1][ct] = w;
        }
        if (rt == rtp && p != k) {
            const float4 v = *(const float4*)(rowK + ct*4);
            const float w0 = v.x, w1 = v.y, w2 = v.z, w3 = v.w;
#define WR(I) { a[I][0] = w0; a[I][1] = w1; a[I][2] = w2; a[I][3] = w3; }
            switch (ip) { ROW_CASES(WR) }
#undef WR
        }
        __syncthreads();                                   // bar3

        // ---- P3: rank-1 elimination (column via wave-local readlane) ----
        const float4 pr = prow[k & 1][ct];
        float dum[16];
#define GETD(J) { _Pragma("unroll") for (int i = 0; i < 16; ++i) dum[i] = __shfl(a[i][J], ctk); }
        if      (jk == 0) GETD(0)
        else if (jk == 1) GETD(1)
        else if (jk == 2) GETD(2)
        else              GETD(3)
#undef GETD
        if (rt == rtk) {                       // pivot row: no self-elimination
#pragma unroll
            for (int i = 0; i < 16; ++i) { if (i == ik) dum[i] = 0.0f; }
        }
        if (ct == ctk) {                       // zero column k first
#define ZCOL(J) { _Pragma("unroll") for (int i = 0; i < 16; ++i) { if (!(rt == rtk && i == ik)) a[i][J] = 0.0f; } }
            if      (jk == 0) ZCOL(0)
            else if (jk == 1) ZCOL(1)
            else if (jk == 2) ZCOL(2)
            else              ZCOL(3)
#undef ZCOL
        }
#pragma unroll
        for (int i = 0; i < 16; ++i) {
            const float d = dum[i];
            a[i][0] = fmaf(-d, pr.x, a[i][0]);
            a[i][1] = fmaf(-d, pr.y, a[i][1]);
            a[i][2] = fmaf(-d, pr.z, a[i][2]);
            a[i][3] = fmaf(-d, pr.w, a[i][3]);
        }
    }
    __syncthreads();
    // ---- net column permutation from the reverse swap sequence ----
    if (tid == 0) {
        for (int c = 0; c < 256; ++c) srccol[c] = c;
        for (int l2 = 255; l2 >= 0; --l2) {
            const int r = indxr[l2];
            if (r != l2) { const int t2 = srccol[r]; srccol[r] = srccol[l2]; srccol[l2] = t2; }
        }
    }
    __syncthreads();
    if (tid < 256) invsrc[srccol[tid]] = tid;
    __syncthreads();
    float* Mo = Minv + (size_t)layer * NU * NU;
#pragma unroll
    for (int i = 0; i < 16; ++i) {
#pragma unroll
        for (int j = 0; j < 4; ++j) {
            Mo[(size_t)(rt*16 + i)*NU + invsrc[ct*4 + j]] = a[i][j];
        }
    }
}

// ---------------------------------------------------------------------------
// fp32 tiled GEMM: C(Mx256) = alpha * Aop @ Bop (+bias), optional second
// output C2 = tanh(result). BM=BN=128, BK=16, 256 threads, 8x8 microtile.
// ---------------------------------------------------------------------------
__device__ __forceinline__ void gemm_body(
    const float* __restrict__ A, const float* __restrict__ Bm,
    float* __restrict__ C, float* __restrict__ C2,
    const float* __restrict__ bias, const float* __restrict__ qv,
    const int K, const int transB, const float alpha)
{
    __shared__ __align__(16) float As[BK][BM];
    __shared__ __align__(16) float Bs[BK][BN];
    const int t  = threadIdx.x;
    const int tx = t & 15, ty = t >> 4;
    const int m0 = blockIdx.x * BM;
    const int n0 = blockIdx.y * BN;

    float acc[8][8];
#pragma unroll
    for (int i = 0; i < 8; ++i)
#pragma unroll
        for (int j = 0; j < 8; ++j) acc[i][j] = 0.0f;

    const int am = t >> 1;
    const int ak = (t & 1) * 8;
    const int bk = t >> 4;
    const int bn = (t & 15) * 8;

    for (int k0 = 0; k0 < K; k0 += BK) {
        const float* Ap = A + (size_t)(m0 + am)*K + (k0 + ak);
        float4 a0 = *(const float4*)(Ap);
        float4 a1 = *(const float4*)(Ap + 4);
        if (qv) {
            a0.x += qv[k0+ak+0]; a0.y += qv[k0+ak+1]; a0.z += qv[k0+ak+2]; a0.w += qv[k0+ak+3];
            a1.x += qv[k0+ak+4]; a1.y += qv[k0+ak+5]; a1.z += qv[k0+ak+6]; a1.w += qv[k0+ak+7];
        }
        As[ak+0][am] = a0.x; As[ak+1][am] = a0.y; As[ak+2][am] = a0.z; As[ak+3][am] = a0.w;
        As[ak+4][am] = a1.x; As[ak+5][am] = a1.y; As[ak+6][am] = a1.z; As[ak+7][am] = a1.w;
        if (!transB) {
            const float* Bp = Bm + (size_t)(k0 + bk)*NU + (n0 + bn);
            const float4 b0 = *(const float4*)(Bp);
            const float4 b1 = *(const float4*)(Bp + 4);
            *(float4*)(&Bs[bk][bn])   = b0;
            *(float4*)(&Bs[bk][bn+4]) = b1;
        } else {
            const float* Bp = Bm + (size_t)(n0 + am)*NU + (k0 + ak);
            const float4 b0 = *(const float4*)(Bp);
            const float4 b1 = *(const float4*)(Bp + 4);
            Bs[ak+0][am] = b0.x; Bs[ak+1][am] = b0.y; Bs[ak+2][am] = b0.z; Bs[ak+3][am] = b0.w;
            Bs[ak+4][am] = b1.x; Bs[ak+5][am] = b1.y; Bs[ak+6][am] = b1.z; Bs[ak+7][am] = b1.w;
        }
        __syncthreads();
#pragma unroll
        for (int kk = 0; kk < BK; ++kk) {
            float af[8], bf[8];
            *(float4*)(af)   = *(const float4*)(&As[kk][ty*8]);
            *(float4*)(af+4) = *(const float4*)(&As[kk][ty*8+4]);
            *(float4*)(bf)   = *(const float4*)(&Bs[kk][tx*8]);
            *(float4*)(bf+4) = *(const float4*)(&Bs[kk][tx*8+4]);
#pragma unroll
            for (int i = 0; i < 8; ++i)
#pragma unroll
                for (int j = 0; j < 8; ++j)
                    acc[i][j] = fmaf(af[i], bf[j], acc[i][j]);
        }
        __syncthreads();
    }

#pragma unroll
    for (int i = 0; i < 8; ++i) {
        const size_t row = m0 + ty*8 + i;
        float o[8];
#pragma unroll
        for (int j = 0; j < 8; ++j) {
            o[j] = alpha * acc[i][j];
            if (bias) o[j] += bias[n0 + tx*8 + j];
        }
        float* cp = C + row*NU + n0 + tx*8;
        float4 v0; v0.x = o[0]; v0.y = o[1]; v0.z = o[2]; v0.w = o[3];
        float4 v1; v1.x = o[4]; v1.y = o[5]; v1.z = o[6]; v1.w = o[7];
        *(float4*)(cp)   = v0;
        *(float4*)(cp+4) = v1;
        if (C2) {
            float* cp2 = C2 + row*NU + n0 + tx*8;
            float4 w0, w1;
            w0.x = tanhf(o[0]); w0.y = tanhf(o[1]); w0.z = tanhf(o[2]); w0.w = tanhf(o[3]);
            w1.x = tanhf(o[4]); w1.y = tanhf(o[5]); w1.z = tanhf(o[6]); w1.w = tanhf(o[7]);
            *(float4*)(cp2)   = w0;
            *(float4*)(cp2+4) = w1;
        }
    }
}

__global__ __launch_bounds__(256) void in_gemm(
    const float* __restrict__ x, const float* __restrict__ Win,
    const float* __restrict__ bin, float* __restrict__ V0, float* __restrict__ V1)
{
    gemm_body(x, Win, V0, V1, bin, nullptr, NDIN, 0, 1.0f);
}

__global__ __launch_bounds__(256) void gemm_nn_neg(
    const float* __restrict__ Ain, const float* __restrict__ M, float* __restrict__ Cout)
{
    gemm_body(Ain, M, Cout, nullptr, nullptr, nullptr, NU, 0, -1.0f);  // V0' = -V1 @ M
}

__global__ __launch_bounds__(256) void gemm_nt_q(
    const float* __restrict__ Ain, const float* __restrict__ M,
    const float* __restrict__ qv, float* __restrict__ Cout)
{
    gemm_body(Ain, M, Cout, nullptr, nullptr, qv, NU, 1, 1.0f);        // V1' = (V0+q) @ M^T
}

// ---------------------------------------------------------------------------
// out = V0 @ W_out + b_out, N=10. One wave per batch row.
// ---------------------------------------------------------------------------
__global__ __launch_bounds__(256) void out_gemm(
    const float* __restrict__ V0, const float* __restrict__ Wout,
    const float* __restrict__ bout, float* __restrict__ out)
{
    __shared__ float Ws[NU*NDOUT];
    const int t = threadIdx.x;
    for (int i = t; i < NU*NDOUT; i += 256) Ws[i] = Wout[i];
    __syncthreads();
    const int lane = t & 63;
    const int wv = t >> 6;
    const int row = blockIdx.x*4 + wv;
    float acc[NDOUT];
#pragma unroll
    for (int j = 0; j < NDOUT; ++j) acc[j] = 0.0f;
#pragma unroll
    for (int s = 0; s < 4; ++s) {
        const int k = lane + 64*s;
        const float v = V0[(size_t)row*NU + k];
#pragma unroll
        for (int j = 0; j < NDOUT; ++j) acc[j] = fmaf(v, Ws[k*NDOUT + j], acc[j]);
    }
#pragma unroll
    for (int off = 32; off > 0; off >>= 1) {
#pragma unroll
        for (int j = 0; j < NDOUT; ++j) acc[j] += __shfl_down(acc[j], off);
    }
    if (lane == 0) {
#pragma unroll
        for (int j = 0; j < NDOUT; ++j) out[(size_t)row*NDOUT + j] = acc[j] + bout[j];
    }
}

extern "C" void kernel_launch(void* const* d_in, const int* in_sizes, int n_in,
                              void* d_out, int out_size, void* d_ws, size_t ws_size,
                              hipStream_t stream)
{
    const float* x    = (const float*)d_in[0];
    const float* Win  = (const float*)d_in[1];
    const float* bin  = (const float*)d_in[2];
    const float* B0   = (const float*)d_in[3];
    const float* q    = (const float*)d_in[4];
    const float* Wout = (const float*)d_in[5];
    const float* bout = (const float*)d_in[6];
    float* out = (float*)d_out;

    float* Minv = (float*)d_ws;
    float* bufA = Minv + (size_t)NLAYERS*NU*NU;
    float* bufB = bufA + (size_t)NBATCH*NU;
    float* bufC = bufB + (size_t)NBATCH*NU;

    const dim3 ggrid(NBATCH/BM, NU/BN);   // 256 x 2 = 512 blocks

    in_gemm<<<ggrid, 256, 0, stream>>>(x, Win, bin, bufA, bufB);       // V0=H, V1=tanh(H)
    invert_kernel<<<NLAYERS, 1024, 0, stream>>>(B0, Minv);

    float* v0 = bufA; float* v1 = bufB; float* fr = bufC;
    for (int l = 0; l < NLAYERS; ++l) {
        const float* Ml = Minv + (size_t)l*NU*NU;
        const float* ql = q + (size_t)l*NU;
        gemm_nn_neg<<<ggrid, 256, 0, stream>>>(v1, Ml, fr);      // newV0 = -V1 @ M
        gemm_nt_q <<<ggrid, 256, 0, stream>>>(v0, Ml, ql, v1);   // newV1 = (V0+q) @ M^T
        float* tswap = v0; v0 = fr; fr = tswap;
    }
    out_gemm<<<NBATCH/4, 256, 0, stream>>>(v0, Wout, bout, out);
}

// Round 6
// 1563.758 us; speedup vs baseline: 1.8657x; 1.8657x over previous
//
#include <hip/hip_runtime.h>
#include <math.h>

#define NU      256
#define NLAYERS 6
#define NBATCH  32768
#define NDIN    784
#define NDOUT   10

#define BM 128
#define BN 128
#define BK 16

// 32-way static-index dispatch over a wave-uniform column index (keeps the
// register array statically indexed; dynamic indices -> scratch/AGPR thrash).
#define COL_CASES(BODY) \
    case 0:  BODY(0);  break; case 1:  BODY(1);  break; \
    case 2:  BODY(2);  break; case 3:  BODY(3);  break; \
    case 4:  BODY(4);  break; case 5:  BODY(5);  break; \
    case 6:  BODY(6);  break; case 7:  BODY(7);  break; \
    case 8:  BODY(8);  break; case 9:  BODY(9);  break; \
    case 10: BODY(10); break; case 11: BODY(11); break; \
    case 12: BODY(12); break; case 13: BODY(13); break; \
    case 14: BODY(14); break; case 15: BODY(15); break; \
    case 16: BODY(16); break; case 17: BODY(17); break; \
    case 18: BODY(18); break; case 19: BODY(19); break; \
    case 20: BODY(20); break; case 21: BODY(21); break; \
    case 22: BODY(22); break; case 23: BODY(23); break; \
    case 24: BODY(24); break; case 25: BODY(25); break; \
    case 26: BODY(26); break; case 27: BODY(27); break; \
    case 28: BODY(28); break; case 29: BODY(29); break; \
    case 30: BODY(30); break; case 31: BODY(31); break;

// ---------------------------------------------------------------------------
// Gauss-Jordan inversion with IMPLICIT partial pivoting (no row swaps).
// One block of 512 threads (8 waves) per layer.
// Layout: lane ct = tid&63 owns rows ct*4+j; wave wv owns cols wv*32+i.
//
// Per iteration k (ONE barrier): phase A (column-owner wave wvk): register-
// local argmax over unused rows -> pivot p; snapshot column k + (p, 1/piv)
// to double-buffered LDS. barrier. Phase B (all waves): rank-1 update.
// CRITICAL (round-5 bug): the column-k special case (zero slots + pivinv
// override) applies ONLY in the owning wave — ikk is wave-local. Unguarded,
// every wave zeroed its own local column ikk each iteration -> garbage.
//
// Output mapping (derived): the no-swap run equals plain in-place GJ on
// B = P A (B row l = physical row p_l), which leaves B^{-1} = A^{-1} P^T in
// place. Hence stored[p_l][c] = A^{-1}[l][p_c], i.e.
//   Minv[ilog[r]][pivrow[c]] = stored[r][c],  ilog[pivrow[k]] = k.
// ---------------------------------------------------------------------------
__global__ __launch_bounds__(512, 2) void invert_kernel(
    const float* __restrict__ B0, float* __restrict__ Minv)
{
    const int layer = blockIdx.x;
    const int tid = threadIdx.x;
    const int ct = tid & 63;     // lane: owns rows ct*4 .. ct*4+3
    const int wv = tid >> 6;     // wave: owns cols wv*32 .. wv*32+31

    __shared__ __align__(16) float colv[2][256];
    __shared__ int   s_p[2];
    __shared__ float s_pv[2];
    __shared__ int   pivrow[256];
    __shared__ int   ilogrow[256];

    // ---- load: a[i][j] = A[ct*4+j][wv*32+i] ----
    float a[32][4];
    const float* Ablk = B0 + (size_t)layer * NU * NU;
#pragma unroll
    for (int j = 0; j < 4; ++j) {
        const float* rp = Ablk + (size_t)(ct*4 + j)*NU + wv*32;
#pragma unroll
        for (int i = 0; i < 32; i += 4) {
            const float4 v = *(const float4*)(rp + i);
            a[i+0][j] = v.x; a[i+1][j] = v.y; a[i+2][j] = v.z; a[i+3][j] = v.w;
        }
    }

    int used = 0;                 // 4-bit mask: my rows already used as pivot

    for (int k = 0; k < 256; ++k) {
        const int wvk = k >> 5, ikk = k & 31, buf = k & 1;

        // ---- Phase A: column owner finds pivot + snapshots column ----
        if (wv == wvk) {
            float c0, c1, c2, c3;
#define EXT(I) { c0 = a[I][0]; c1 = a[I][1]; c2 = a[I][2]; c3 = a[I][3]; }
            switch (ikk) { COL_CASES(EXT) }
#undef EXT
            float ba = -1.0f, bv = 1.0f; int br = 0;
            {
                float av;
                av = (used & 1) ? -1.0f : fabsf(c0);
                if (av > ba) { ba = av; bv = c0; br = ct*4 + 0; }
                av = (used & 2) ? -1.0f : fabsf(c1);
                if (av > ba) { ba = av; bv = c1; br = ct*4 + 1; }
                av = (used & 4) ? -1.0f : fabsf(c2);
                if (av > ba) { ba = av; bv = c2; br = ct*4 + 2; }
                av = (used & 8) ? -1.0f : fabsf(c3);
                if (av > ba) { ba = av; bv = c3; br = ct*4 + 3; }
            }
#pragma unroll
            for (int off = 32; off > 0; off >>= 1) {
                const float oa = __shfl_down(ba, off);
                const float ov = __shfl_down(bv, off);
                const int   orr = __shfl_down(br, off);
                if (oa > ba) { ba = oa; bv = ov; br = orr; }
            }
            float4 cw; cw.x = c0; cw.y = c1; cw.z = c2; cw.w = c3;
            *(float4*)(&colv[buf][ct*4]) = cw;
            if (ct == 0) {
                s_p[buf] = br;
                s_pv[buf] = 1.0f / bv;
                pivrow[k] = br;
            }
        }
        __syncthreads();

        // ---- Phase B: rank-1 elimination ----
        const int   p      = __builtin_amdgcn_readfirstlane(s_p[buf]);  // scalar
        const float pivinv = s_pv[buf];
        const int ctp = p >> 2, jp = p & 3;

        const float4 dv = *(const float4*)(&colv[buf][ct*4]);

        // pivot row values for my 32 columns: lane ctp holds them at slot jp
        float t[32];
#define SEL(J) { _Pragma("unroll") for (int i = 0; i < 32; ++i) t[i] = a[i][J]; }
        switch (jp) {
            case 0: SEL(0) break; case 1: SEL(1) break;
            case 2: SEL(2) break; default: SEL(3) break;
        }
#undef SEL
        float prw[32];
#pragma unroll
        for (int i = 0; i < 32; ++i) prw[i] = __shfl(t[i], ctp) * pivinv;

        // column-k special case: ONLY in the owning wave (ikk is wave-local!)
        if (wv == wvk) {
#define ZCOL(I) { prw[I] = pivinv; a[I][0] = 0.0f; a[I][1] = 0.0f; a[I][2] = 0.0f; a[I][3] = 0.0f; }
            switch (ikk) { COL_CASES(ZCOL) }
#undef ZCOL
        }

        const float d0 = -dv.x, d1 = -dv.y, d2 = -dv.z, d3 = -dv.w;
#pragma unroll
        for (int i = 0; i < 32; ++i) {
            const float pw = prw[i];
            a[i][0] = fmaf(d0, pw, a[i][0]);
            a[i][1] = fmaf(d1, pw, a[i][1]);
            a[i][2] = fmaf(d2, pw, a[i][2]);
            a[i][3] = fmaf(d3, pw, a[i][3]);
        }

        // overwrite pivot row (lane ctp, slot jp) with scaled row prw
        const bool mine = (ct == ctp);
#define OWR(J) { _Pragma("unroll") for (int i = 0; i < 32; ++i) a[i][J] = mine ? prw[i] : a[i][J]; }
        switch (jp) {
            case 0: OWR(0) break; case 1: OWR(1) break;
            case 2: OWR(2) break; default: OWR(3) break;
        }
#undef OWR
        if (mine) used |= (1 << jp);
    }
    __syncthreads();

    // ---- direct permutation: Minv[ilog[r]][pivrow[c]] = stored[r][c] ----
    if (tid < 256) ilogrow[pivrow[tid]] = tid;
    __syncthreads();

    float* Mo = Minv + (size_t)layer * NU * NU;
#pragma unroll
    for (int j = 0; j < 4; ++j) {
        const int orow = ilogrow[ct*4 + j];
#pragma unroll
        for (int i = 0; i < 32; ++i) {
            Mo[(size_t)orow*NU + pivrow[wv*32 + i]] = a[i][j];
        }
    }
}

// ---------------------------------------------------------------------------
// fp32 tiled GEMM: C(Mx256) = alpha * Aop @ Bop (+bias), optional second
// output C2 = tanh(result). BM=BN=128, BK=16, 256 threads, 8x8 microtile.
// ---------------------------------------------------------------------------
__device__ __forceinline__ void gemm_body(
    const float* __restrict__ A, const float* __restrict__ Bm,
    float* __restrict__ C, float* __restrict__ C2,
    const float* __restrict__ bias, const float* __restrict__ qv,
    const int K, const int transB, const float alpha)
{
    __shared__ __align__(16) float As[BK][BM];
    __shared__ __align__(16) float Bs[BK][BN];
    const int t  = threadIdx.x;
    const int tx = t & 15, ty = t >> 4;
    const int m0 = blockIdx.x * BM;
    const int n0 = blockIdx.y * BN;

    float acc[8][8];
#pragma unroll
    for (int i = 0; i < 8; ++i)
#pragma unroll
        for (int j = 0; j < 8; ++j) acc[i][j] = 0.0f;

    const int am = t >> 1;
    const int ak = (t & 1) * 8;
    const int bk = t >> 4;
    const int bn = (t & 15) * 8;

    for (int k0 = 0; k0 < K; k0 += BK) {
        const float* Ap = A + (size_t)(m0 + am)*K + (k0 + ak);
        float4 a0 = *(const float4*)(Ap);
        float4 a1 = *(const float4*)(Ap + 4);
        if (qv) {
            a0.x += qv[k0+ak+0]; a0.y += qv[k0+ak+1]; a0.z += qv[k0+ak+2]; a0.w += qv[k0+ak+3];
            a1.x += qv[k0+ak+4]; a1.y += qv[k0+ak+5]; a1.z += qv[k0+ak+6]; a1.w += qv[k0+ak+7];
        }
        As[ak+0][am] = a0.x; As[ak+1][am] = a0.y; As[ak+2][am] = a0.z; As[ak+3][am] = a0.w;
        As[ak+4][am] = a1.x; As[ak+5][am] = a1.y; As[ak+6][am] = a1.z; As[ak+7][am] = a1.w;
        if (!transB) {
            const float* Bp = Bm + (size_t)(k0 + bk)*NU + (n0 + bn);
            const float4 b0 = *(const float4*)(Bp);
            const float4 b1 = *(const float4*)(Bp + 4);
            *(float4*)(&Bs[bk][bn])   = b0;
            *(float4*)(&Bs[bk][bn+4]) = b1;
        } else {
            const float* Bp = Bm + (size_t)(n0 + am)*NU + (k0 + ak);
            const float4 b0 = *(const float4*)(Bp);
            const float4 b1 = *(const float4*)(Bp + 4);
            Bs[ak+0][am] = b0.x; Bs[ak+1][am] = b0.y; Bs[ak+2][am] = b0.z; Bs[ak+3][am] = b0.w;
            Bs[ak+4][am] = b1.x; Bs[ak+5][am] = b1.y; Bs[ak+6][am] = b1.z; Bs[ak+7][am] = b1.w;
        }
        __syncthreads();
#pragma unroll
        for (int kk = 0; kk < BK; ++kk) {
            float af[8], bf[8];
            *(float4*)(af)   = *(const float4*)(&As[kk][ty*8]);
            *(float4*)(af+4) = *(const float4*)(&As[kk][ty*8+4]);
            *(float4*)(bf)   = *(const float4*)(&Bs[kk][tx*8]);
            *(float4*)(bf+4) = *(const float4*)(&Bs[kk][tx*8+4]);
#pragma unroll
            for (int i = 0; i < 8; ++i)
#pragma unroll
                for (int j = 0; j < 8; ++j)
                    acc[i][j] = fmaf(af[i], bf[j], acc[i][j]);
        }
        __syncthreads();
    }

#pragma unroll
    for (int i = 0; i < 8; ++i) {
        const size_t row = m0 + ty*8 + i;
        float o[8];
#pragma unroll
        for (int j = 0; j < 8; ++j) {
            o[j] = alpha * acc[i][j];
            if (bias) o[j] += bias[n0 + tx*8 + j];
        }
        float* cp = C + row*NU + n0 + tx*8;
        float4 v0; v0.x = o[0]; v0.y = o[1]; v0.z = o[2]; v0.w = o[3];
        float4 v1; v1.x = o[4]; v1.y = o[5]; v1.z = o[6]; v1.w = o[7];
        *(float4*)(cp)   = v0;
        *(float4*)(cp+4) = v1;
        if (C2) {
            float* cp2 = C2 + row*NU + n0 + tx*8;
            float4 w0, w1;
            w0.x = tanhf(o[0]); w0.y = tanhf(o[1]); w0.z = tanhf(o[2]); w0.w = tanhf(o[3]);
            w1.x = tanhf(o[4]); w1.y = tanhf(o[5]); w1.z = tanhf(o[6]); w1.w = tanhf(o[7]);
            *(float4*)(cp2)   = w0;
            *(float4*)(cp2+4) = w1;
        }
    }
}

__global__ __launch_bounds__(256) void in_gemm(
    const float* __restrict__ x, const float* __restrict__ Win,
    const float* __restrict__ bin, float* __restrict__ V0, float* __restrict__ V1)
{
    gemm_body(x, Win, V0, V1, bin, nullptr, NDIN, 0, 1.0f);
}

__global__ __launch_bounds__(256) void gemm_nn_neg(
    const float* __restrict__ Ain, const float* __restrict__ M, float* __restrict__ Cout)
{
    gemm_body(Ain, M, Cout, nullptr, nullptr, nullptr, NU, 0, -1.0f);  // V0' = -V1 @ M
}

__global__ __launch_bounds__(256) void gemm_nt_q(
    const float* __restrict__ Ain, const float* __restrict__ M,
    const float* __restrict__ qv, float* __restrict__ Cout)
{
    gemm_body(Ain, M, Cout, nullptr, nullptr, qv, NU, 1, 1.0f);        // V1' = (V0+q) @ M^T
}

// ---------------------------------------------------------------------------
// out = V0 @ W_out + b_out, N=10. One wave per batch row.
// ---------------------------------------------------------------------------
__global__ __launch_bounds__(256) void out_gemm(
    const float* __restrict__ V0, const float* __restrict__ Wout,
    const float* __restrict__ bout, float* __restrict__ out)
{
    __shared__ float Ws[NU*NDOUT];
    const int t = threadIdx.x;
    for (int i = t; i < NU*NDOUT; i += 256) Ws[i] = Wout[i];
    __syncthreads();
    const int lane = t & 63;
    const int wv = t >> 6;
    const int row = blockIdx.x*4 + wv;
    float acc[NDOUT];
#pragma unroll
    for (int j = 0; j < NDOUT; ++j) acc[j] = 0.0f;
#pragma unroll
    for (int s = 0; s < 4; ++s) {
        const int k = lane + 64*s;
        const float v = V0[(size_t)row*NU + k];
#pragma unroll
        for (int j = 0; j < NDOUT; ++j) acc[j] = fmaf(v, Ws[k*NDOUT + j], acc[j]);
    }
#pragma unroll
    for (int off = 32; off > 0; off >>= 1) {
#pragma unroll
        for (int j = 0; j < NDOUT; ++j) acc[j] += __shfl_down(acc[j], off);
    }
    if (lane == 0) {
#pragma unroll
        for (int j = 0; j < NDOUT; ++j) out[(size_t)row*NDOUT + j] = acc[j] + bout[j];
    }
}

extern "C" void kernel_launch(void* const* d_in, const int* in_sizes, int n_in,
                              void* d_out, int out_size, void* d_ws, size_t ws_size,
                              hipStream_t stream)
{
    const float* x    = (const float*)d_in[0];
    const float* Win  = (const float*)d_in[1];
    const float* bin  = (const float*)d_in[2];
    const float* B0   = (const float*)d_in[3];
    const float* q    = (const float*)d_in[4];
    const float* Wout = (const float*)d_in[5];
    const float* bout = (const float*)d_in[6];
    float* out = (float*)d_out;

    float* Minv = (float*)d_ws;
    float* bufA = Minv + (size_t)NLAYERS*NU*NU;
    float* bufB = bufA + (size_t)NBATCH*NU;
    float* bufC = bufB + (size_t)NBATCH*NU;

    const dim3 ggrid(NBATCH/BM, NU/BN);   // 256 x 2 = 512 blocks

    in_gemm<<<ggrid, 256, 0, stream>>>(x, Win, bin, bufA, bufB);       // V0=H, V1=tanh(H)
    invert_kernel<<<NLAYERS, 512, 0, stream>>>(B0, Minv);

    float* v0 = bufA; float* v1 = bufB; float* fr = bufC;
    for (int l = 0; l < NLAYERS; ++l) {
        const float* Ml = Minv + (size_t)l*NU*NU;
        const float* ql = q + (size_t)l*NU;
        gemm_nn_neg<<<ggrid, 256, 0, stream>>>(v1, Ml, fr);      // newV0 = -V1 @ M
        gemm_nt_q <<<ggrid, 256, 0, stream>>>(v0, Ml, ql, v1);   // newV1 = (V0+q) @ M^T
        float* tswap = v0; v0 = fr; fr = tswap;
    }
    out_gemm<<<NBATCH/4, 256, 0, stream>>>(v0, Wout, bout, out);
}

// Round 7
// 1201.770 us; speedup vs baseline: 2.4277x; 1.3012x over previous
//
#include <hip/hip_runtime.h>
#include <math.h>

#define NU      256
#define NLAYERS 6
#define NBATCH  32768
#define NDIN    784
#define NDOUT   10
#define NUSQ    65536

typedef unsigned short u16;
typedef __attribute__((ext_vector_type(8))) short s16x8;
typedef __attribute__((ext_vector_type(4))) float f32x4;

// bf16 helpers (RNE)
__device__ __forceinline__ u16 f2bf(float x) {
    union { float f; unsigned u; } a; a.f = x;
    const unsigned r = a.u + 0x7fffu + ((a.u >> 16) & 1u);
    return (u16)(r >> 16);
}
__device__ __forceinline__ float bf2f(u16 h) {
    union { unsigned u; float f; } a; a.u = ((unsigned)h) << 16; return a.f;
}

// 32-way static-index dispatch over a wave-uniform column index.
#define COL_CASES(BODY) \
    case 0:  BODY(0);  break; case 1:  BODY(1);  break; \
    case 2:  BODY(2);  break; case 3:  BODY(3);  break; \
    case 4:  BODY(4);  break; case 5:  BODY(5);  break; \
    case 6:  BODY(6);  break; case 7:  BODY(7);  break; \
    case 8:  BODY(8);  break; case 9:  BODY(9);  break; \
    case 10: BODY(10); break; case 11: BODY(11); break; \
    case 12: BODY(12); break; case 13: BODY(13); break; \
    case 14: BODY(14); break; case 15: BODY(15); break; \
    case 16: BODY(16); break; case 17: BODY(17); break; \
    case 18: BODY(18); break; case 19: BODY(19); break; \
    case 20: BODY(20); break; case 21: BODY(21); break; \
    case 22: BODY(22); break; case 23: BODY(23); break; \
    case 24: BODY(24); break; case 25: BODY(25); break; \
    case 26: BODY(26); break; case 27: BODY(27); break; \
    case 28: BODY(28); break; case 29: BODY(29); break; \
    case 30: BODY(30); break; case 31: BODY(31); break;

// ---------------------------------------------------------------------------
// Gauss-Jordan inversion with IMPLICIT partial pivoting (proven round-6).
// NEW epilogue: writes M in both GEMM B-layouts as split-bf16 planes
//   wnt[n][k] = M[n][k]  (for W = M^T in C = A@W:  B-tile stage [n][k])
//   wnn[n][k] = M[k][n]  (for W = M)
// and computes bq = M q (the rank-1 fold of the per-layer q bias).
// ---------------------------------------------------------------------------
__global__ __launch_bounds__(512, 2) void invert_kernel(
    const float* __restrict__ B0, const float* __restrict__ qg,
    u16* __restrict__ wnnh, u16* __restrict__ wnnl,
    u16* __restrict__ wnth, u16* __restrict__ wntl,
    float* __restrict__ bq)
{
    const int layer = blockIdx.x;
    const int tid = threadIdx.x;
    const int ct = tid & 63;     // lane: owns rows ct*4 .. ct*4+3
    const int wv = tid >> 6;     // wave: owns cols wv*32 .. wv*32+31

    __shared__ __align__(16) float colv[2][256];
    __shared__ int   s_p[2];
    __shared__ float s_pv[2];
    __shared__ int   pivrow[256];
    __shared__ int   ilogrow[256];
    __shared__ float qs[256];
    __shared__ float part[8][256];

    float a[32][4];
    const float* Ablk = B0 + (size_t)layer * NU * NU;
#pragma unroll
    for (int j = 0; j < 4; ++j) {
        const float* rp = Ablk + (size_t)(ct*4 + j)*NU + wv*32;
#pragma unroll
        for (int i = 0; i < 32; i += 4) {
            const float4 v = *(const float4*)(rp + i);
            a[i+0][j] = v.x; a[i+1][j] = v.y; a[i+2][j] = v.z; a[i+3][j] = v.w;
        }
    }

    int used = 0;

    for (int k = 0; k < 256; ++k) {
        const int wvk = k >> 5, ikk = k & 31, buf = k & 1;

        if (wv == wvk) {
            float c0, c1, c2, c3;
#define EXT(I) { c0 = a[I][0]; c1 = a[I][1]; c2 = a[I][2]; c3 = a[I][3]; }
            switch (ikk) { COL_CASES(EXT) }
#undef EXT
            float ba = -1.0f, bv = 1.0f; int br = 0;
            {
                float av;
                av = (used & 1) ? -1.0f : fabsf(c0);
                if (av > ba) { ba = av; bv = c0; br = ct*4 + 0; }
                av = (used & 2) ? -1.0f : fabsf(c1);
                if (av > ba) { ba = av; bv = c1; br = ct*4 + 1; }
                av = (used & 4) ? -1.0f : fabsf(c2);
                if (av > ba) { ba = av; bv = c2; br = ct*4 + 2; }
                av = (used & 8) ? -1.0f : fabsf(c3);
                if (av > ba) { ba = av; bv = c3; br = ct*4 + 3; }
            }
#pragma unroll
            for (int off = 32; off > 0; off >>= 1) {
                const float oa = __shfl_down(ba, off);
                const float ov = __shfl_down(bv, off);
                const int   orr = __shfl_down(br, off);
                if (oa > ba) { ba = oa; bv = ov; br = orr; }
            }
            float4 cw; cw.x = c0; cw.y = c1; cw.z = c2; cw.w = c3;
            *(float4*)(&colv[buf][ct*4]) = cw;
            if (ct == 0) {
                s_p[buf] = br;
                s_pv[buf] = 1.0f / bv;
                pivrow[k] = br;
            }
        }
        __syncthreads();

        const int   p      = __builtin_amdgcn_readfirstlane(s_p[buf]);
        const float pivinv = s_pv[buf];
        const int ctp = p >> 2, jp = p & 3;

        const float4 dv = *(const float4*)(&colv[buf][ct*4]);

        float t[32];
#define SEL(J) { _Pragma("unroll") for (int i = 0; i < 32; ++i) t[i] = a[i][J]; }
        switch (jp) {
            case 0: SEL(0) break; case 1: SEL(1) break;
            case 2: SEL(2) break; default: SEL(3) break;
        }
#undef SEL
        float prw[32];
#pragma unroll
        for (int i = 0; i < 32; ++i) prw[i] = __shfl(t[i], ctp) * pivinv;

        if (wv == wvk) {   // column-k special case ONLY in the owning wave
#define ZCOL(I) { prw[I] = pivinv; a[I][0] = 0.0f; a[I][1] = 0.0f; a[I][2] = 0.0f; a[I][3] = 0.0f; }
            switch (ikk) { COL_CASES(ZCOL) }
#undef ZCOL
        }

        const float d0 = -dv.x, d1 = -dv.y, d2 = -dv.z, d3 = -dv.w;
#pragma unroll
        for (int i = 0; i < 32; ++i) {
            const float pw = prw[i];
            a[i][0] = fmaf(d0, pw, a[i][0]);
            a[i][1] = fmaf(d1, pw, a[i][1]);
            a[i][2] = fmaf(d2, pw, a[i][2]);
            a[i][3] = fmaf(d3, pw, a[i][3]);
        }

        const bool mine = (ct == ctp);
#define OWR(J) { _Pragma("unroll") for (int i = 0; i < 32; ++i) a[i][J] = mine ? prw[i] : a[i][J]; }
        switch (jp) {
            case 0: OWR(0) break; case 1: OWR(1) break;
            case 2: OWR(2) break; default: OWR(3) break;
        }
#undef OWR
        if (mine) used |= (1 << jp);
    }
    __syncthreads();

    // stored a[i][j] = M[r][c], r = ilog[ct*4+j], c = pivrow[wv*32+i]
    if (tid < 256) { ilogrow[pivrow[tid]] = tid; qs[tid] = qg[(size_t)layer*NU + tid]; }
    __syncthreads();

    // ---- bq = M q ----
    {
        float s0=0.f, s1=0.f, s2=0.f, s3=0.f;
#pragma unroll
        for (int i = 0; i < 32; ++i) {
            const float qq = qs[pivrow[wv*32 + i]];
            s0 = fmaf(a[i][0], qq, s0);
            s1 = fmaf(a[i][1], qq, s1);
            s2 = fmaf(a[i][2], qq, s2);
            s3 = fmaf(a[i][3], qq, s3);
        }
        part[wv][ct*4+0] = s0; part[wv][ct*4+1] = s1;
        part[wv][ct*4+2] = s2; part[wv][ct*4+3] = s3;
    }
    __syncthreads();
    if (tid < 256) {
        float s = 0.f;
#pragma unroll
        for (int w2 = 0; w2 < 8; ++w2) s += part[w2][tid];
        bq[(size_t)layer*NU + ilogrow[tid]] = s;
    }

    // ---- split-bf16 W planes ----
    u16* nh = wnnh + (size_t)layer*NUSQ; u16* nl = wnnl + (size_t)layer*NUSQ;
    u16* th = wnth + (size_t)layer*NUSQ; u16* tl = wntl + (size_t)layer*NUSQ;
#pragma unroll
    for (int j = 0; j < 4; ++j) {
        const int r = ilogrow[ct*4 + j];
#pragma unroll
        for (int i = 0; i < 32; ++i) {
            const int c = pivrow[wv*32 + i];
            const float v = a[i][j];
            const u16 h  = f2bf(v);
            const u16 lo = f2bf(v - bf2f(h));
            th[(size_t)r*NU + c] = h;  tl[(size_t)r*NU + c] = lo;  // wnt[n][k]=M[n][k]
            nh[(size_t)c*NU + r] = h;  nl[(size_t)c*NU + r] = lo;  // wnn[n][k]=M[k][n]
        }
    }
}

// ---------------------------------------------------------------------------
// Split-bf16 MFMA GEMM: C(32768x256) = alpha * A @ W (+bias), A and C as
// hi/lo bf16 plane pairs, W given as [n][k] planes (m97 gemm_bt layout).
// 128x128 tile, BK=32, 256 thr (4 waves), wave = 64x64 = 4x4 MFMA 16x16x32.
// Split product: hh + hl + lh (lo*lo ~ 2^-18, dropped).
// Frag layouts (HW-verified per guide): A[m=lane&15][k=(lane>>4)*8+j];
// B[n=lane&15][k=(lane>>4)*8+j]; C col=lane&15, row=(lane>>4)*4+reg.
// ---------------------------------------------------------------------------
__global__ __launch_bounds__(256, 2) void gemm_mfma(
    const u16* __restrict__ Ah, const u16* __restrict__ Al,
    const u16* __restrict__ Bh, const u16* __restrict__ Bl,
    u16* __restrict__ Ch, u16* __restrict__ Cl,
    const float* __restrict__ bias, const float alpha)
{
    __shared__ __align__(16) u16 lAh[128*32], lAl[128*32], lBh[128*32], lBl[128*32];
    const int t    = threadIdx.x;
    const int lane = t & 63;
    const int w    = t >> 6;
    const int wr = w >> 1, wc = w & 1;
    const int qd = lane >> 4, l15 = lane & 15;
    const int m0 = blockIdx.x * 128, n0 = blockIdx.y * 128;

    const int srow = t >> 2;          // 0..63
    const int skc  = (t & 3) * 8;     // 0,8,16,24

    f32x4 acc[4][4];
    const f32x4 z = {0.f, 0.f, 0.f, 0.f};
#pragma unroll
    for (int i = 0; i < 4; ++i)
#pragma unroll
        for (int j = 0; j < 4; ++j) acc[i][j] = z;

    for (int k0 = 0; k0 < NU; k0 += 32) {
#pragma unroll
        for (int half = 0; half < 2; ++half) {
            const int rr = srow + half*64;
            const size_t ga = (size_t)(m0 + rr)*NU + k0 + skc;
            const size_t gb = (size_t)(n0 + rr)*NU + k0 + skc;
            *(s16x8*)&lAh[rr*32 + skc] = *(const s16x8*)&Ah[ga];
            *(s16x8*)&lAl[rr*32 + skc] = *(const s16x8*)&Al[ga];
            *(s16x8*)&lBh[rr*32 + skc] = *(const s16x8*)&Bh[gb];
            *(s16x8*)&lBl[rr*32 + skc] = *(const s16x8*)&Bl[gb];
        }
        __syncthreads();

        s16x8 ah[4], al[4], bh[4], bl[4];
#pragma unroll
        for (int mt = 0; mt < 4; ++mt) {
            const int off = (wr*64 + mt*16 + l15)*32 + qd*8;
            ah[mt] = *(const s16x8*)&lAh[off];
            al[mt] = *(const s16x8*)&lAl[off];
        }
#pragma unroll
        for (int nt = 0; nt < 4; ++nt) {
            const int off = (wc*64 + nt*16 + l15)*32 + qd*8;
            bh[nt] = *(const s16x8*)&lBh[off];
            bl[nt] = *(const s16x8*)&lBl[off];
        }
#pragma unroll
        for (int mt = 0; mt < 4; ++mt)
#pragma unroll
            for (int nt = 0; nt < 4; ++nt) {
                acc[mt][nt] = __builtin_amdgcn_mfma_f32_16x16x32_bf16(ah[mt], bh[nt], acc[mt][nt], 0, 0, 0);
                acc[mt][nt] = __builtin_amdgcn_mfma_f32_16x16x32_bf16(ah[mt], bl[nt], acc[mt][nt], 0, 0, 0);
                acc[mt][nt] = __builtin_amdgcn_mfma_f32_16x16x32_bf16(al[mt], bh[nt], acc[mt][nt], 0, 0, 0);
            }
        __syncthreads();
    }

#pragma unroll
    for (int mt = 0; mt < 4; ++mt) {
#pragma unroll
        for (int nt = 0; nt < 4; ++nt) {
            const int col = n0 + wc*64 + nt*16 + l15;
            const float bb = bias ? bias[col] : 0.0f;
#pragma unroll
            for (int r = 0; r < 4; ++r) {
                const int row = m0 + wr*64 + mt*16 + qd*4 + r;
                const float v = alpha*acc[mt][nt][r] + bb;
                const u16 h  = f2bf(v);
                const u16 lo = f2bf(v - bf2f(h));
                const size_t o = (size_t)row*NU + col;
                Ch[o] = h; Cl[o] = lo;
            }
        }
    }
}

// ---------------------------------------------------------------------------
// in_gemm: fp32 tiled GEMM (K=784) with bias; epilogue writes V0 = H and
// V1 = tanh(H) as split-bf16 plane pairs. BM=BN=128, BK=16, 8x8 microtile.
// ---------------------------------------------------------------------------
__global__ __launch_bounds__(256) void in_gemm(
    const float* __restrict__ A, const float* __restrict__ Bm,
    const float* __restrict__ bias,
    u16* __restrict__ V0h, u16* __restrict__ V0l,
    u16* __restrict__ V1h, u16* __restrict__ V1l)
{
    __shared__ __align__(16) float As[16][128];
    __shared__ __align__(16) float Bs[16][128];
    const int t  = threadIdx.x;
    const int tx = t & 15, ty = t >> 4;
    const int m0 = blockIdx.x * 128;
    const int n0 = blockIdx.y * 128;
    const int K = NDIN;

    float acc[8][8];
#pragma unroll
    for (int i = 0; i < 8; ++i)
#pragma unroll
        for (int j = 0; j < 8; ++j) acc[i][j] = 0.0f;

    const int am = t >> 1;
    const int ak = (t & 1) * 8;
    const int bk = t >> 4;
    const int bn = (t & 15) * 8;

    for (int k0 = 0; k0 < K; k0 += 16) {
        const float* Ap = A + (size_t)(m0 + am)*K + (k0 + ak);
        const float4 a0 = *(const float4*)(Ap);
        const float4 a1 = *(const float4*)(Ap + 4);
        As[ak+0][am] = a0.x; As[ak+1][am] = a0.y; As[ak+2][am] = a0.z; As[ak+3][am] = a0.w;
        As[ak+4][am] = a1.x; As[ak+5][am] = a1.y; As[ak+6][am] = a1.z; As[ak+7][am] = a1.w;
        const float* Bp = Bm + (size_t)(k0 + bk)*NU + (n0 + bn);
        const float4 b0 = *(const float4*)(Bp);
        const float4 b1 = *(const float4*)(Bp + 4);
        *(float4*)(&Bs[bk][bn])   = b0;
        *(float4*)(&Bs[bk][bn+4]) = b1;
        __syncthreads();
#pragma unroll
        for (int kk = 0; kk < 16; ++kk) {
            float af[8], bf[8];
            *(float4*)(af)   = *(const float4*)(&As[kk][ty*8]);
            *(float4*)(af+4) = *(const float4*)(&As[kk][ty*8+4]);
            *(float4*)(bf)   = *(const float4*)(&Bs[kk][tx*8]);
            *(float4*)(bf+4) = *(const float4*)(&Bs[kk][tx*8+4]);
#pragma unroll
            for (int i = 0; i < 8; ++i)
#pragma unroll
                for (int j = 0; j < 8; ++j)
                    acc[i][j] = fmaf(af[i], bf[j], acc[i][j]);
        }
        __syncthreads();
    }

#pragma unroll
    for (int i = 0; i < 8; ++i) {
        const size_t row = m0 + ty*8 + i;
        s16x8 vh, vl, th, tl;
#pragma unroll
        for (int j = 0; j < 8; ++j) {
            const float v = acc[i][j] + bias[n0 + tx*8 + j];
            const u16 h  = f2bf(v);
            vh[j] = (short)h; vl[j] = (short)f2bf(v - bf2f(h));
            const float tv = tanhf(v);
            const u16 h2 = f2bf(tv);
            th[j] = (short)h2; tl[j] = (short)f2bf(tv - bf2f(h2));
        }
        const size_t o = row*NU + n0 + tx*8;
        *(s16x8*)&V0h[o] = vh; *(s16x8*)&V0l[o] = vl;
        *(s16x8*)&V1h[o] = th; *(s16x8*)&V1l[o] = tl;
    }
}

// ---------------------------------------------------------------------------
// out = V0 @ W_out + b_out, N=10. One wave per batch row; V0 from planes.
// ---------------------------------------------------------------------------
__global__ __launch_bounds__(256) void out_gemm(
    const u16* __restrict__ V0h, const u16* __restrict__ V0l,
    const float* __restrict__ Wout,
    const float* __restrict__ bout, float* __restrict__ out)
{
    __shared__ float Ws[NU*NDOUT];
    const int t = threadIdx.x;
    for (int i = t; i < NU*NDOUT; i += 256) Ws[i] = Wout[i];
    __syncthreads();
    const int lane = t & 63;
    const int wv = t >> 6;
    const int row = blockIdx.x*4 + wv;
    float acc[NDOUT];
#pragma unroll
    for (int j = 0; j < NDOUT; ++j) acc[j] = 0.0f;
#pragma unroll
    for (int s = 0; s < 4; ++s) {
        const int k = lane + 64*s;
        const size_t o = (size_t)row*NU + k;
        const float v = bf2f(V0h[o]) + bf2f(V0l[o]);
#pragma unroll
        for (int j = 0; j < NDOUT; ++j) acc[j] = fmaf(v, Ws[k*NDOUT + j], acc[j]);
    }
#pragma unroll
    for (int off = 32; off > 0; off >>= 1) {
#pragma unroll
        for (int j = 0; j < NDOUT; ++j) acc[j] += __shfl_down(acc[j], off);
    }
    if (lane == 0) {
#pragma unroll
        for (int j = 0; j < NDOUT; ++j) out[(size_t)row*NDOUT + j] = acc[j] + bout[j];
    }
}

extern "C" void kernel_launch(void* const* d_in, const int* in_sizes, int n_in,
                              void* d_out, int out_size, void* d_ws, size_t ws_size,
                              hipStream_t stream)
{
    const float* x    = (const float*)d_in[0];
    const float* Win  = (const float*)d_in[1];
    const float* bin  = (const float*)d_in[2];
    const float* B0   = (const float*)d_in[3];
    const float* q    = (const float*)d_in[4];
    const float* Wout = (const float*)d_in[5];
    const float* bout = (const float*)d_in[6];
    float* out = (float*)d_out;

    // workspace carve (~104 MB)
    u16* wnnh = (u16*)d_ws;
    u16* wnnl = wnnh + (size_t)NLAYERS*NUSQ;
    u16* wnth = wnnl + (size_t)NLAYERS*NUSQ;
    u16* wntl = wnth + (size_t)NLAYERS*NUSQ;
    float* bq = (float*)(wntl + (size_t)NLAYERS*NUSQ);
    u16* pl   = (u16*)(bq + NLAYERS*NU);
    const size_t PSZ = (size_t)NBATCH*NU;
    u16* sAh = pl;           u16* sAl = sAh + PSZ;   // slot A (V0)
    u16* sBh = sAl + PSZ;    u16* sBl = sBh + PSZ;   // slot B (V1)
    u16* sCh = sBl + PSZ;    u16* sCl = sCh + PSZ;   // slot C (free)

    const dim3 ggrid(NBATCH/128, NU/128);   // 256 x 2

    in_gemm<<<ggrid, 256, 0, stream>>>(x, Win, bin, sAh, sAl, sBh, sBl); // V0=H, V1=tanh
    invert_kernel<<<NLAYERS, 512, 0, stream>>>(B0, q, wnnh, wnnl, wnth, wntl, bq);

    u16 *v0h = sAh, *v0l = sAl, *v1h = sBh, *v1l = sBl, *frh = sCh, *frl = sCl;
    for (int l = 0; l < NLAYERS; ++l) {
        const size_t wo = (size_t)l*NUSQ;
        // newV0 = -V1 @ M
        gemm_mfma<<<ggrid, 256, 0, stream>>>(v1h, v1l, wnnh + wo, wnnl + wo,
                                             frh, frl, nullptr, -1.0f);
        // newV1 = V0 @ M^T + (Mq)^T
        gemm_mfma<<<ggrid, 256, 0, stream>>>(v0h, v0l, wnth + wo, wntl + wo,
                                             v1h, v1l, bq + (size_t)l*NU, 1.0f);
        u16* t0 = v0h; u16* t1 = v0l;
        v0h = frh; v0l = frl; frh = t0; frl = t1;
    }
    out_gemm<<<NBATCH/4, 256, 0, stream>>>(v0h, v0l, Wout, bout, out);
}

// Round 8
// 1016.175 us; speedup vs baseline: 2.8711x; 1.1826x over previous
//
#include <hip/hip_runtime.h>
#include <math.h>

#define NU      256
#define NLAYERS 6
#define NBATCH  32768
#define NDIN    784
#define NDOUT   10
#define NUSQ    65536

typedef unsigned short u16;
typedef __attribute__((ext_vector_type(8))) short s16x8;
typedef __attribute__((ext_vector_type(4))) float f32x4;

// bf16 helpers (RNE)
__device__ __forceinline__ u16 f2bf(float x) {
    union { float f; unsigned u; } a; a.f = x;
    const unsigned r = a.u + 0x7fffu + ((a.u >> 16) & 1u);
    return (u16)(r >> 16);
}
__device__ __forceinline__ float bf2f(u16 h) {
    union { unsigned u; float f; } a; a.u = ((unsigned)h) << 16; return a.f;
}

// async global->LDS, 16 B per lane (m97 pattern; LDS dest = wave base + lane*16)
__device__ __forceinline__ void gl_lds16(const u16* g, u16* l) {
    __builtin_amdgcn_global_load_lds(
        (const __attribute__((address_space(1))) void*)g,
        (__attribute__((address_space(3))) void*)l, 16, 0, 0);
}

// 32-way static-index dispatch over a wave-uniform column index.
#define COL_CASES(BODY) \
    case 0:  BODY(0);  break; case 1:  BODY(1);  break; \
    case 2:  BODY(2);  break; case 3:  BODY(3);  break; \
    case 4:  BODY(4);  break; case 5:  BODY(5);  break; \
    case 6:  BODY(6);  break; case 7:  BODY(7);  break; \
    case 8:  BODY(8);  break; case 9:  BODY(9);  break; \
    case 10: BODY(10); break; case 11: BODY(11); break; \
    case 12: BODY(12); break; case 13: BODY(13); break; \
    case 14: BODY(14); break; case 15: BODY(15); break; \
    case 16: BODY(16); break; case 17: BODY(17); break; \
    case 18: BODY(18); break; case 19: BODY(19); break; \
    case 20: BODY(20); break; case 21: BODY(21); break; \
    case 22: BODY(22); break; case 23: BODY(23); break; \
    case 24: BODY(24); break; case 25: BODY(25); break; \
    case 26: BODY(26); break; case 27: BODY(27); break; \
    case 28: BODY(28); break; case 29: BODY(29); break; \
    case 30: BODY(30); break; case 31: BODY(31); break;

// ---------------------------------------------------------------------------
// Fused first kernel: blocks 0..5 = GJ inversion (proven round-6/7 body,
// 512 threads); blocks 6..517 = in_gemm (proven fp32 body, threads>=256 exit).
// The two are input/output-disjoint, so fusing just makes them concurrent
// (in_gemm's ~205us hides under invert's ~610us on the other 250 CUs).
// ---------------------------------------------------------------------------
__global__ __launch_bounds__(512, 2) void fused_inv_ingemm(
    const float* __restrict__ B0, const float* __restrict__ qg,
    u16* __restrict__ wnnh, u16* __restrict__ wnnl,
    u16* __restrict__ wnth, u16* __restrict__ wntl,
    float* __restrict__ bq,
    const float* __restrict__ X, const float* __restrict__ Win,
    const float* __restrict__ bin,
    u16* __restrict__ V0h, u16* __restrict__ V0l,
    u16* __restrict__ V1h, u16* __restrict__ V1l)
{
    // ---- invert LDS ----
    __shared__ __align__(16) float colv[2][256];
    __shared__ int   s_p[2];
    __shared__ float s_pv[2];
    __shared__ int   pivrow[256];
    __shared__ int   ilogrow[256];
    __shared__ float qs[256];
    __shared__ float part[8][256];
    // ---- in_gemm LDS ----
    __shared__ __align__(16) float As[16][128];
    __shared__ __align__(16) float Bs[16][128];

    const int tid = threadIdx.x;

    if (blockIdx.x < NLAYERS) {
        // =================== inversion path ===================
        const int layer = blockIdx.x;
        const int ct = tid & 63;     // lane: owns rows ct*4 .. ct*4+3
        const int wv = tid >> 6;     // wave: owns cols wv*32 .. wv*32+31

        float a[32][4];
        const float* Ablk = B0 + (size_t)layer * NU * NU;
#pragma unroll
        for (int j = 0; j < 4; ++j) {
            const float* rp = Ablk + (size_t)(ct*4 + j)*NU + wv*32;
#pragma unroll
            for (int i = 0; i < 32; i += 4) {
                const float4 v = *(const float4*)(rp + i);
                a[i+0][j] = v.x; a[i+1][j] = v.y; a[i+2][j] = v.z; a[i+3][j] = v.w;
            }
        }

        int used = 0;

        for (int k = 0; k < 256; ++k) {
            const int wvk = k >> 5, ikk = k & 31, buf = k & 1;

            if (wv == wvk) {
                float c0, c1, c2, c3;
#define EXT(I) { c0 = a[I][0]; c1 = a[I][1]; c2 = a[I][2]; c3 = a[I][3]; }
                switch (ikk) { COL_CASES(EXT) }
#undef EXT
                float ba = -1.0f, bv = 1.0f; int br = 0;
                {
                    float av;
                    av = (used & 1) ? -1.0f : fabsf(c0);
                    if (av > ba) { ba = av; bv = c0; br = ct*4 + 0; }
                    av = (used & 2) ? -1.0f : fabsf(c1);
                    if (av > ba) { ba = av; bv = c1; br = ct*4 + 1; }
                    av = (used & 4) ? -1.0f : fabsf(c2);
                    if (av > ba) { ba = av; bv = c2; br = ct*4 + 2; }
                    av = (used & 8) ? -1.0f : fabsf(c3);
                    if (av > ba) { ba = av; bv = c3; br = ct*4 + 3; }
                }
#pragma unroll
                for (int off = 32; off > 0; off >>= 1) {
                    const float oa = __shfl_down(ba, off);
                    const float ov = __shfl_down(bv, off);
                    const int   orr = __shfl_down(br, off);
                    if (oa > ba) { ba = oa; bv = ov; br = orr; }
                }
                float4 cw; cw.x = c0; cw.y = c1; cw.z = c2; cw.w = c3;
                *(float4*)(&colv[buf][ct*4]) = cw;
                if (ct == 0) {
                    s_p[buf] = br;
                    s_pv[buf] = 1.0f / bv;
                    pivrow[k] = br;
                }
            }
            __syncthreads();

            const int   p      = __builtin_amdgcn_readfirstlane(s_p[buf]);
            const float pivinv = s_pv[buf];
            const int ctp = p >> 2, jp = p & 3;

            const float4 dv = *(const float4*)(&colv[buf][ct*4]);

            float t[32];
#define SEL(J) { _Pragma("unroll") for (int i = 0; i < 32; ++i) t[i] = a[i][J]; }
            switch (jp) {
                case 0: SEL(0) break; case 1: SEL(1) break;
                case 2: SEL(2) break; default: SEL(3) break;
            }
#undef SEL
            float prw[32];
#pragma unroll
            for (int i = 0; i < 32; ++i) prw[i] = __shfl(t[i], ctp) * pivinv;

            if (wv == wvk) {   // column-k special case ONLY in the owning wave
#define ZCOL(I) { prw[I] = pivinv; a[I][0] = 0.0f; a[I][1] = 0.0f; a[I][2] = 0.0f; a[I][3] = 0.0f; }
                switch (ikk) { COL_CASES(ZCOL) }
#undef ZCOL
            }

            const float d0 = -dv.x, d1 = -dv.y, d2 = -dv.z, d3 = -dv.w;
#pragma unroll
            for (int i = 0; i < 32; ++i) {
                const float pw = prw[i];
                a[i][0] = fmaf(d0, pw, a[i][0]);
                a[i][1] = fmaf(d1, pw, a[i][1]);
                a[i][2] = fmaf(d2, pw, a[i][2]);
                a[i][3] = fmaf(d3, pw, a[i][3]);
            }

            const bool mine = (ct == ctp);
#define OWR(J) { _Pragma("unroll") for (int i = 0; i < 32; ++i) a[i][J] = mine ? prw[i] : a[i][J]; }
            switch (jp) {
                case 0: OWR(0) break; case 1: OWR(1) break;
                case 2: OWR(2) break; default: OWR(3) break;
            }
#undef OWR
            if (mine) used |= (1 << jp);
        }
        __syncthreads();

        // stored a[i][j] = M[r][c], r = ilog[ct*4+j], c = pivrow[wv*32+i]
        if (tid < 256) { ilogrow[pivrow[tid]] = tid; qs[tid] = qg[(size_t)layer*NU + tid]; }
        __syncthreads();

        // ---- bq = M q ----
        {
            float s0=0.f, s1=0.f, s2=0.f, s3=0.f;
#pragma unroll
            for (int i = 0; i < 32; ++i) {
                const float qq = qs[pivrow[wv*32 + i]];
                s0 = fmaf(a[i][0], qq, s0);
                s1 = fmaf(a[i][1], qq, s1);
                s2 = fmaf(a[i][2], qq, s2);
                s3 = fmaf(a[i][3], qq, s3);
            }
            part[wv][ct*4+0] = s0; part[wv][ct*4+1] = s1;
            part[wv][ct*4+2] = s2; part[wv][ct*4+3] = s3;
        }
        __syncthreads();
        if (tid < 256) {
            float s = 0.f;
#pragma unroll
            for (int w2 = 0; w2 < 8; ++w2) s += part[w2][tid];
            bq[(size_t)layer*NU + ilogrow[tid]] = s;
        }

        // ---- split-bf16 W planes ----
        u16* nh = wnnh + (size_t)layer*NUSQ; u16* nl = wnnl + (size_t)layer*NUSQ;
        u16* th = wnth + (size_t)layer*NUSQ; u16* tl = wntl + (size_t)layer*NUSQ;
#pragma unroll
        for (int j = 0; j < 4; ++j) {
            const int r = ilogrow[ct*4 + j];
#pragma unroll
            for (int i = 0; i < 32; ++i) {
                const int c = pivrow[wv*32 + i];
                const float v = a[i][j];
                const u16 h  = f2bf(v);
                const u16 lo = f2bf(v - bf2f(h));
                th[(size_t)r*NU + c] = h;  tl[(size_t)r*NU + c] = lo;  // wnt[n][k]=M[n][k]
                nh[(size_t)c*NU + r] = h;  nl[(size_t)c*NU + r] = lo;  // wnn[n][k]=M[k][n]
            }
        }
        return;
    }

    // =================== in_gemm path (256 active threads) ===================
    if (tid >= 256) return;   // exited waves free their slots; HW barrier counts rest

    const int bid = blockIdx.x - NLAYERS;
    const int m0 = (bid & 255) * 128;
    const int n0 = (bid >> 8) * 128;
    const int t  = tid;
    const int tx = t & 15, ty = t >> 4;
    const int K = NDIN;

    float acc[8][8];
#pragma unroll
    for (int i = 0; i < 8; ++i)
#pragma unroll
        for (int j = 0; j < 8; ++j) acc[i][j] = 0.0f;

    const int am = t >> 1;
    const int ak = (t & 1) * 8;
    const int bk = t >> 4;
    const int bn = (t & 15) * 8;

    for (int k0 = 0; k0 < K; k0 += 16) {
        const float* Ap = X + (size_t)(m0 + am)*K + (k0 + ak);
        const float4 a0 = *(const float4*)(Ap);
        const float4 a1 = *(const float4*)(Ap + 4);
        As[ak+0][am] = a0.x; As[ak+1][am] = a0.y; As[ak+2][am] = a0.z; As[ak+3][am] = a0.w;
        As[ak+4][am] = a1.x; As[ak+5][am] = a1.y; As[ak+6][am] = a1.z; As[ak+7][am] = a1.w;
        const float* Bp = Win + (size_t)(k0 + bk)*NU + (n0 + bn);
        const float4 b0 = *(const float4*)(Bp);
        const float4 b1 = *(const float4*)(Bp + 4);
        *(float4*)(&Bs[bk][bn])   = b0;
        *(float4*)(&Bs[bk][bn+4]) = b1;
        __syncthreads();
#pragma unroll
        for (int kk = 0; kk < 16; ++kk) {
            float af[8], bf[8];
            *(float4*)(af)   = *(const float4*)(&As[kk][ty*8]);
            *(float4*)(af+4) = *(const float4*)(&As[kk][ty*8+4]);
            *(float4*)(bf)   = *(const float4*)(&Bs[kk][tx*8]);
            *(float4*)(bf+4) = *(const float4*)(&Bs[kk][tx*8+4]);
#pragma unroll
            for (int i = 0; i < 8; ++i)
#pragma unroll
                for (int j = 0; j < 8; ++j)
                    acc[i][j] = fmaf(af[i], bf[j], acc[i][j]);
        }
        __syncthreads();
    }

#pragma unroll
    for (int i = 0; i < 8; ++i) {
        const size_t row = m0 + ty*8 + i;
        s16x8 vh, vl, th2, tl2;
#pragma unroll
        for (int j = 0; j < 8; ++j) {
            const float v = acc[i][j] + bin[n0 + tx*8 + j];
            const u16 h  = f2bf(v);
            vh[j] = (short)h; vl[j] = (short)f2bf(v - bf2f(h));
            const float tv = tanhf(v);
            const u16 h2 = f2bf(tv);
            th2[j] = (short)h2; tl2[j] = (short)f2bf(tv - bf2f(h2));
        }
        const size_t o = row*NU + n0 + tx*8;
        *(s16x8*)&V0h[o] = vh; *(s16x8*)&V0l[o] = vl;
        *(s16x8*)&V1h[o] = th2; *(s16x8*)&V1l[o] = tl2;
    }
}

// ---------------------------------------------------------------------------
// Split-bf16 MFMA GEMM: C(32768x256) = alpha * A @ W (+bias). Staging via
// async global_load_lds width=16 (lane-contiguous LDS mapping: thread t <->
// LDS bytes [16t,16t+16) per plane buffer). 128x128 tile, BK=32, 4 waves,
// wave = 64x64 = 4x4 MFMA 16x16x32. Split product hh + hl + lh.
// ---------------------------------------------------------------------------
__global__ __launch_bounds__(256, 2) void gemm_mfma(
    const u16* __restrict__ Ah, const u16* __restrict__ Al,
    const u16* __restrict__ Bh, const u16* __restrict__ Bl,
    u16* __restrict__ Ch, u16* __restrict__ Cl,
    const float* __restrict__ bias, const float alpha)
{
    __shared__ __align__(16) u16 lAh[128*32], lAl[128*32], lBh[128*32], lBl[128*32];
    const int t    = threadIdx.x;
    const int lane = t & 63;
    const int w    = t >> 6;
    const int wr = w >> 1, wc = w & 1;
    const int qd = lane >> 4, l15 = lane & 15;
    const int m0 = blockIdx.x * 128, n0 = blockIdx.y * 128;

    const int srow = t >> 2;          // 0..63
    const int skc  = (t & 3) * 8;     // 0,8,16,24

    f32x4 acc[4][4];
    const f32x4 z = {0.f, 0.f, 0.f, 0.f};
#pragma unroll
    for (int i = 0; i < 4; ++i)
#pragma unroll
        for (int j = 0; j < 4; ++j) acc[i][j] = z;

    for (int k0 = 0; k0 < NU; k0 += 32) {
#pragma unroll
        for (int half = 0; half < 2; ++half) {
            const int rr = srow + half*64;
            const size_t ga = (size_t)(m0 + rr)*NU + k0 + skc;
            const size_t gb = (size_t)(n0 + rr)*NU + k0 + skc;
            const int lo = rr*32 + skc;
            gl_lds16(Ah + ga, &lAh[lo]);
            gl_lds16(Al + ga, &lAl[lo]);
            gl_lds16(Bh + gb, &lBh[lo]);
            gl_lds16(Bl + gb, &lBl[lo]);
        }
        __syncthreads();

        s16x8 ah[4], al[4], bh[4], bl[4];
#pragma unroll
        for (int mt = 0; mt < 4; ++mt) {
            const int off = (wr*64 + mt*16 + l15)*32 + qd*8;
            ah[mt] = *(const s16x8*)&lAh[off];
            al[mt] = *(const s16x8*)&lAl[off];
        }
#pragma unroll
        for (int nt = 0; nt < 4; ++nt) {
            const int off = (wc*64 + nt*16 + l15)*32 + qd*8;
            bh[nt] = *(const s16x8*)&lBh[off];
            bl[nt] = *(const s16x8*)&lBl[off];
        }
#pragma unroll
        for (int mt = 0; mt < 4; ++mt)
#pragma unroll
            for (int nt = 0; nt < 4; ++nt) {
                acc[mt][nt] = __builtin_amdgcn_mfma_f32_16x16x32_bf16(ah[mt], bh[nt], acc[mt][nt], 0, 0, 0);
                acc[mt][nt] = __builtin_amdgcn_mfma_f32_16x16x32_bf16(ah[mt], bl[nt], acc[mt][nt], 0, 0, 0);
                acc[mt][nt] = __builtin_amdgcn_mfma_f32_16x16x32_bf16(al[mt], bh[nt], acc[mt][nt], 0, 0, 0);
            }
        __syncthreads();
    }

#pragma unroll
    for (int mt = 0; mt < 4; ++mt) {
#pragma unroll
        for (int nt = 0; nt < 4; ++nt) {
            const int col = n0 + wc*64 + nt*16 + l15;
            const float bb = bias ? bias[col] : 0.0f;
#pragma unroll
            for (int r = 0; r < 4; ++r) {
                const int row = m0 + wr*64 + mt*16 + qd*4 + r;
                const float v = alpha*acc[mt][nt][r] + bb;
                const u16 h  = f2bf(v);
                const u16 lo = f2bf(v - bf2f(h));
                const size_t o = (size_t)row*NU + col;
                Ch[o] = h; Cl[o] = lo;
            }
        }
    }
}

// ---------------------------------------------------------------------------
// out = V0 @ W_out + b_out, N=10. One wave per batch row; V0 from planes.
// ---------------------------------------------------------------------------
__global__ __launch_bounds__(256) void out_gemm(
    const u16* __restrict__ V0h, const u16* __restrict__ V0l,
    const float* __restrict__ Wout,
    const float* __restrict__ bout, float* __restrict__ out)
{
    __shared__ float Ws[NU*NDOUT];
    const int t = threadIdx.x;
    for (int i = t; i < NU*NDOUT; i += 256) Ws[i] = Wout[i];
    __syncthreads();
    const int lane = t & 63;
    const int wv = t >> 6;
    const int row = blockIdx.x*4 + wv;
    float acc[NDOUT];
#pragma unroll
    for (int j = 0; j < NDOUT; ++j) acc[j] = 0.0f;
#pragma unroll
    for (int s = 0; s < 4; ++s) {
        const int k = lane + 64*s;
        const size_t o = (size_t)row*NU + k;
        const float v = bf2f(V0h[o]) + bf2f(V0l[o]);
#pragma unroll
        for (int j = 0; j < NDOUT; ++j) acc[j] = fmaf(v, Ws[k*NDOUT + j], acc[j]);
    }
#pragma unroll
    for (int off = 32; off > 0; off >>= 1) {
#pragma unroll
        for (int j = 0; j < NDOUT; ++j) acc[j] += __shfl_down(acc[j], off);
    }
    if (lane == 0) {
#pragma unroll
        for (int j = 0; j < NDOUT; ++j) out[(size_t)row*NDOUT + j] = acc[j] + bout[j];
    }
}

extern "C" void kernel_launch(void* const* d_in, const int* in_sizes, int n_in,
                              void* d_out, int out_size, void* d_ws, size_t ws_size,
                              hipStream_t stream)
{
    const float* x    = (const float*)d_in[0];
    const float* Win  = (const float*)d_in[1];
    const float* bin  = (const float*)d_in[2];
    const float* B0   = (const float*)d_in[3];
    const float* q    = (const float*)d_in[4];
    const float* Wout = (const float*)d_in[5];
    const float* bout = (const float*)d_in[6];
    float* out = (float*)d_out;

    // workspace carve (~104 MB)
    u16* wnnh = (u16*)d_ws;
    u16* wnnl = wnnh + (size_t)NLAYERS*NUSQ;
    u16* wnth = wnnl + (size_t)NLAYERS*NUSQ;
    u16* wntl = wnth + (size_t)NLAYERS*NUSQ;
    float* bq = (float*)(wntl + (size_t)NLAYERS*NUSQ);
    u16* pl   = (u16*)(bq + NLAYERS*NU);
    const size_t PSZ = (size_t)NBATCH*NU;
    u16* sAh = pl;           u16* sAl = sAh + PSZ;   // slot A (V0)
    u16* sBh = sAl + PSZ;    u16* sBl = sBh + PSZ;   // slot B (V1)
    u16* sCh = sBl + PSZ;    u16* sCl = sCh + PSZ;   // slot C (free)

    // fused: 6 invert blocks + 512 in_gemm blocks, concurrent
    fused_inv_ingemm<<<NLAYERS + 512, 512, 0, stream>>>(
        B0, q, wnnh, wnnl, wnth, wntl, bq,
        x, Win, bin, sAh, sAl, sBh, sBl);

    const dim3 ggrid(NBATCH/128, NU/128);   // 256 x 2

    u16 *v0h = sAh, *v0l = sAl, *v1h = sBh, *v1l = sBl, *frh = sCh, *frl = sCl;
    for (int l = 0; l < NLAYERS; ++l) {
        const size_t wo = (size_t)l*NUSQ;
        // newV0 = -V1 @ M
        gemm_mfma<<<ggrid, 256, 0, stream>>>(v1h, v1l, wnnh + wo, wnnl + wo,
                                             frh, frl, nullptr, -1.0f);
        // newV1 = V0 @ M^T + (Mq)^T
        gemm_mfma<<<ggrid, 256, 0, stream>>>(v0h, v0l, wnth + wo, wntl + wo,
                                             v1h, v1l, bq + (size_t)l*NU, 1.0f);
        u16* t0 = v0h; u16* t1 = v0l;
        v0h = frh; v0l = frl; frh = t0; frl = t1;
    }
    out_gemm<<<NBATCH/4, 256, 0, stream>>>(v0h, v0l, Wout, bout, out);
}